// Round 13
// baseline (132.296 us; speedup 1.0000x reference)
//
#include <hip/hip_runtime.h>
#include <math.h>

#define B_   8
#define C_   64
#define CK_  8
#define L_   4096

typedef __attribute__((ext_vector_type(8))) __bf16 bf16x8;
typedef __attribute__((ext_vector_type(4))) __bf16 bf16x4;
typedef __attribute__((ext_vector_type(4))) float  f32x4;

// ---------------- Kernel 1: QKV projection -> bf16 ----------------
// (byte-identical to the r8 hardware-verified version)
__global__ __launch_bounds__(256) void qkv_kernel(
    const float* __restrict__ x,
    const float* __restrict__ Wq, const float* __restrict__ bq,
    const float* __restrict__ Wk, const float* __restrict__ bk,
    const float* __restrict__ Wv, const float* __restrict__ bv,
    __bf16* __restrict__ qo, __bf16* __restrict__ ko, __bf16* __restrict__ vpack)
{
    __shared__ float LWq[CK_ * C_];
    __shared__ float LWk[CK_ * C_];
    __shared__ float LWv[C_ * C_];      // row-major [c_out][c_in]
    __shared__ __bf16 Lqs[64 * 8];
    __shared__ __bf16 Lks[64 * 8];

    const int tid = threadIdx.x;
    if (tid < 128) {
        ((float4*)LWq)[tid] = ((const float4*)Wq)[tid];
        ((float4*)LWk)[tid] = ((const float4*)Wk)[tid];
    }
    #pragma unroll
    for (int j = 0; j < 4; ++j)
        ((float4*)LWv)[tid + j * 256] = ((const float4*)Wv)[tid + j * 256];
    __syncthreads();

    const int b  = blockIdx.x >> 6;
    const int t  = blockIdx.x & 63;
    const int l0 = t << 6;
    const int lg = tid & 15;
    const int g  = tid >> 4;

    float va[4][4];
    float qk[4];
    #pragma unroll
    for (int j = 0; j < 4; ++j) {
        float bb = bv[4 * g + j];
        va[j][0] = bb; va[j][1] = bb; va[j][2] = bb; va[j][3] = bb;
    }
    {
        float bb = (g < 8) ? bq[g] : bk[g - 8];
        qk[0] = bb; qk[1] = bb; qk[2] = bb; qk[3] = bb;
    }
    const float* wqk = (g < 8) ? (LWq + g * C_) : (LWk + (g - 8) * C_);

    const float* xp = x + ((size_t)b * C_) * L_ + l0 + lg * 4;
    #pragma unroll 4
    for (int c4 = 0; c4 < 16; ++c4) {
        float4 xv[4];
        #pragma unroll
        for (int u = 0; u < 4; ++u)
            xv[u] = *(const float4*)(xp + (size_t)(4 * c4 + u) * L_);
        #pragma unroll
        for (int j = 0; j < 4; ++j) {
            float4 wv = ((const float4*)(LWv + (4 * g + j) * C_))[c4];
            float* a = va[j];
            a[0]=fmaf(wv.x,xv[0].x,a[0]); a[1]=fmaf(wv.x,xv[0].y,a[1]); a[2]=fmaf(wv.x,xv[0].z,a[2]); a[3]=fmaf(wv.x,xv[0].w,a[3]);
            a[0]=fmaf(wv.y,xv[1].x,a[0]); a[1]=fmaf(wv.y,xv[1].y,a[1]); a[2]=fmaf(wv.y,xv[1].z,a[2]); a[3]=fmaf(wv.y,xv[1].w,a[3]);
            a[0]=fmaf(wv.z,xv[2].x,a[0]); a[1]=fmaf(wv.z,xv[2].y,a[1]); a[2]=fmaf(wv.z,xv[2].z,a[2]); a[3]=fmaf(wv.z,xv[2].w,a[3]);
            a[0]=fmaf(wv.w,xv[3].x,a[0]); a[1]=fmaf(wv.w,xv[3].y,a[1]); a[2]=fmaf(wv.w,xv[3].z,a[2]); a[3]=fmaf(wv.w,xv[3].w,a[3]);
        }
        {
            float4 wv = ((const float4*)wqk)[c4];
            qk[0]=fmaf(wv.x,xv[0].x,qk[0]); qk[1]=fmaf(wv.x,xv[0].y,qk[1]); qk[2]=fmaf(wv.x,xv[0].z,qk[2]); qk[3]=fmaf(wv.x,xv[0].w,qk[3]);
            qk[0]=fmaf(wv.y,xv[1].x,qk[0]); qk[1]=fmaf(wv.y,xv[1].y,qk[1]); qk[2]=fmaf(wv.y,xv[1].z,qk[2]); qk[3]=fmaf(wv.y,xv[1].w,qk[3]);
            qk[0]=fmaf(wv.z,xv[2].x,qk[0]); qk[1]=fmaf(wv.z,xv[2].y,qk[1]); qk[2]=fmaf(wv.z,xv[2].z,qk[2]); qk[3]=fmaf(wv.z,xv[2].w,qk[3]);
            qk[0]=fmaf(wv.w,xv[3].x,qk[0]); qk[1]=fmaf(wv.w,xv[3].y,qk[1]); qk[2]=fmaf(wv.w,xv[3].z,qk[2]); qk[3]=fmaf(wv.w,xv[3].w,qk[3]);
        }
    }

    // vpack stores: thread (g,lg) holds c=4g+j, l=l0+4lg+u.
    {
        __bf16* vt = vpack + ((size_t)b * 64 + t) * 4096;
        const int cb = g >> 2;
        const int sg = lg >> 2;
        const int qd = lg & 3;
        #pragma unroll
        for (int j = 0; j < 4; ++j) {
            bf16x4 vv;
            vv[0]=(__bf16)va[j][0]; vv[1]=(__bf16)va[j][1]; vv[2]=(__bf16)va[j][2]; vv[3]=(__bf16)va[j][3];
            *(bf16x4*)(vt + ((size_t)((cb * 4 + sg) * 64 + qd * 16 + (g & 3) * 4 + j)) * 4) = vv;
        }
    }
    // q/k: gather through LDS, then b128 stores
    #pragma unroll
    for (int u = 0; u < 4; ++u) {
        if (g < 8) Lqs[(lg * 4 + u) * 8 + g]       = (__bf16)qk[u];
        else       Lks[(lg * 4 + u) * 8 + (g - 8)] = (__bf16)qk[u];
    }
    __syncthreads();
    if (tid < 64) {
        *(bf16x8*)(qo + ((size_t)b * L_ + l0 + tid) * 8) = *(bf16x8*)(Lqs + tid * 8);
        *(bf16x8*)(ko + ((size_t)b * L_ + l0 + tid) * 8) = *(bf16x8*)(Lks + tid * 8);
    }
}

// ---------------- Kernel 2: fused attention ------------------------------
// r12 structure with ONE delta: SINGLE-buffered LDS (32.5 KB vs 64.5 KB)
// -> 4 blocks/CU instead of 2 (32 waves/CU, 100% wave occupancy) to hide
// the per-iter latency stalls (r12: 35-50% idle at 16 waves/CU). Costs one
// extra barrier per iter: read phase | bar | ds_write next tile | bar.
// Stage loads for i+1 still issued at compute(i) start (full phase of VMEM
// lead time). No new registers (r9/r11 spill lesson). XCD swizzle kept.
__global__ __launch_bounds__(512, 4) void attn_kernel(
    const __bf16* __restrict__ q, const __bf16* __restrict__ kT,
    const __bf16* __restrict__ VP, const float* __restrict__ x,
    const float* __restrict__ gamma_p, float* __restrict__ out)
{
    __shared__ __bf16 Lv[4][4096];      // 32 KB single buffer
    __shared__ float  csA[8][16];

    const int tid  = threadIdx.x;
    const int w    = tid >> 6;
    const int lane = tid & 63;
    const int quad = lane >> 4;
    const int l16  = lane & 15;
    const int wh   = w & 3;
    const int lh   = w >> 2;
    const int wg   = blockIdx.x;
    const int b    = wg & 7;            // XCD swizzle (FETCH 26->9.8 MB, r12)
    const int mb   = wg >> 3;
    const int m0   = mb << 6;

    const __bf16* vp = VP + (size_t)b * (64 * 4096);
    const __bf16* qb = q  + (size_t)b * L_ * CK_;

    bf16x8 kf = {};
    if (quad == 0) kf = *(const bf16x8*)(kT + ((size_t)b * L_ + m0 + wh * 16 + l16) * CK_);

    // staging shares: u = w*4+k (0..31): tl = u>>3, seg = u&7.
    const __bf16* gk[4];
    int ok[4];
    #pragma unroll
    for (int k = 0; k < 4; ++k) {
        const int u = w * 4 + k, tl = u >> 3, seg = u & 7;
        gk[k] = vp + (size_t)((tl & 1) * 32 + (tl >> 1)) * 4096 + seg * 512 + lane * 8;
        ok[k] = tl * 4096 + seg * 512 + lane * 8;
    }

    f32x4 acc[4] = {};
    float csum = 0.f;
    bf16x8 r[4];

    // prologue: stage iter 0
    #pragma unroll
    for (int k = 0; k < 4; ++k) r[k] = *(const bf16x8*)gk[k];
    #pragma unroll
    for (int k = 0; k < 4; ++k) *(bf16x8*)(&Lv[0][0] + ok[k]) = r[k];

    for (int i = 0; i < 16; ++i) {
        __syncthreads();    // publish ds_writes (prologue or prev iter end)

        if (i < 15) {       // issue next-iter V loads early (land under compute)
            #pragma unroll
            for (int k = 0; k < 4; ++k)
                r[k] = *(const bf16x8*)(gk[k] + (size_t)(i + 1) * 8192);
        }

        // broadcast q loads for the pair (tiles lh*32+2i, lh*32+2i+1)
        bf16x8 qA[4], qB[4];
        #pragma unroll
        for (int sg = 0; sg < 4; ++sg) {
            qA[sg] = *(const bf16x8*)(qb + (size_t)((lh * 32 + 2 * i)     * 64 + sg * 16 + l16) * CK_);
            qB[sg] = *(const bf16x8*)(qb + (size_t)((lh * 32 + 2 * i + 1) * 64 + sg * 16 + l16) * CK_);
        }

        bf16x4 pkA[4], pkB[4];
        #pragma unroll
        for (int sg = 0; sg < 4; ++sg) {
            f32x4 sv = __builtin_amdgcn_mfma_f32_16x16x32_bf16(qA[sg], kf, (f32x4){0.f,0.f,0.f,0.f}, 0, 0, 0);
            const float e0 = __expf(sv[0]);
            const float e1 = __expf(sv[1]);
            const float e2 = __expf(sv[2]);
            const float e3 = __expf(sv[3]);
            csum += (e0 + e1) + (e2 + e3);
            pkA[sg][0]=(__bf16)e0; pkA[sg][1]=(__bf16)e1; pkA[sg][2]=(__bf16)e2; pkA[sg][3]=(__bf16)e3;
        }
        #pragma unroll
        for (int sg = 0; sg < 4; ++sg) {
            f32x4 sv = __builtin_amdgcn_mfma_f32_16x16x32_bf16(qB[sg], kf, (f32x4){0.f,0.f,0.f,0.f}, 0, 0, 0);
            const float e0 = __expf(sv[0]);
            const float e1 = __expf(sv[1]);
            const float e2 = __expf(sv[2]);
            const float e3 = __expf(sv[3]);
            csum += (e0 + e1) + (e2 + e3);
            pkB[sg][0]=(__bf16)e0; pkB[sg][1]=(__bf16)e1; pkB[sg][2]=(__bf16)e2; pkB[sg][3]=(__bf16)e3;
        }

        const __bf16* LbA = &Lv[lh][0];
        const __bf16* LbB = &Lv[2 + lh][0];
        #pragma unroll
        for (int sg = 0; sg < 4; ++sg) {
            bf16x8 p8 = __builtin_shufflevector(pkA[sg], pkB[sg], 0, 1, 2, 3, 4, 5, 6, 7);
            #pragma unroll
            for (int cb = 0; cb < 4; ++cb) {
                bf16x4 vfA = *(const bf16x4*)(LbA + ((size_t)((cb * 4 + sg) * 64 + lane)) * 4);
                bf16x4 vfB = *(const bf16x4*)(LbB + ((size_t)((cb * 4 + sg) * 64 + lane)) * 4);
                bf16x8 a8 = __builtin_shufflevector(vfA, vfB, 0, 1, 2, 3, 4, 5, 6, 7);
                acc[cb] = __builtin_amdgcn_mfma_f32_16x16x32_bf16(a8, p8, acc[cb], 0, 0, 0);
            }
        }

        __syncthreads();    // all V reads of this iter done
        if (i < 15) {       // overwrite the single buffer for iter i+1
            #pragma unroll
            for (int k = 0; k < 4; ++k)
                *(bf16x8*)(&Lv[0][0] + ok[k]) = r[k];
        }
    }

    // ---- epilogue: reduce lh=1 into lh=0, normalize, residual ----
    // Last loop barrier ended all V reads; Lv reusable as Sc (16 KB).
    float* Sc = (float*)&Lv[0][0];
    if (lh == 1) {
        #pragma unroll
        for (int cb = 0; cb < 4; ++cb)
            #pragma unroll
            for (int r2 = 0; r2 < 4; ++r2)
                Sc[(wh * 64 + cb * 16 + quad * 4 + r2) * 16 + l16] = acc[cb][r2];
    }
    csum += __shfl_xor(csum, 16);
    csum += __shfl_xor(csum, 32);
    if (quad == 0) csA[w][l16] = csum;
    __syncthreads();

    if (lh == 0) {
        const float rinv = gamma_p[0] / (csA[wh][l16] + csA[wh + 4][l16]);
        #pragma unroll
        for (int cb = 0; cb < 4; ++cb) {
            #pragma unroll
            for (int r2 = 0; r2 < 4; ++r2) {
                const int c = cb * 16 + quad * 4 + r2;
                const float vsum = acc[cb][r2] + Sc[(wh * 64 + c) * 16 + l16];
                const size_t idx = ((size_t)(b * 64 + c)) * L_ + m0 + wh * 16 + l16;
                out[idx] = fmaf(rinv, vsum, x[idx]);
            }
        }
    }
}

extern "C" void kernel_launch(void* const* d_in, const int* in_sizes, int n_in,
                              void* d_out, int out_size, void* d_ws, size_t ws_size,
                              hipStream_t stream) {
    const float* x  = (const float*)d_in[0];
    const float* Wq = (const float*)d_in[1];
    const float* bq = (const float*)d_in[2];
    const float* Wk = (const float*)d_in[3];
    const float* bk = (const float*)d_in[4];
    const float* Wv = (const float*)d_in[5];
    const float* bv = (const float*)d_in[6];
    const float* gm = (const float*)d_in[7];
    float* out = (float*)d_out;

    __bf16* ws    = (__bf16*)d_ws;
    __bf16* qo    = ws;                         // 262144 bf16
    __bf16* ko    = ws + 262144;                // 262144 bf16
    __bf16* vpack = ws + 524288;                // 2097152 bf16

    qkv_kernel<<<dim3(B_ * (L_ / 64)), dim3(256), 0, stream>>>(
        x, Wq, bq, Wk, bk, Wv, bv, qo, ko, vpack);
    attn_kernel<<<dim3(B_ * 64), dim3(512), 0, stream>>>(
        qo, ko, vpack, x, gm, out);
}

// Round 14
// 125.469 us; speedup vs baseline: 1.0544x; 1.0544x over previous
//
#include <hip/hip_runtime.h>
#include <math.h>

#define B_   8
#define C_   64
#define CK_  8
#define L_   4096

typedef __attribute__((ext_vector_type(8))) __bf16 bf16x8;
typedef __attribute__((ext_vector_type(4))) __bf16 bf16x4;
typedef __attribute__((ext_vector_type(4))) float  f32x4;

// ---------------- Kernel 1: QKV projection -> bf16 ----------------
// r8-verified math/layout; ONE structural delta: the 64x64 x-tile is staged
// in LDS once (coalesced, 16 floats/thread) and fragments are read from LDS,
// replacing the old 16x-redundant global re-reads (256 KB L1 traffic/block).
__global__ __launch_bounds__(256) void qkv_kernel(
    const float* __restrict__ x,
    const float* __restrict__ Wq, const float* __restrict__ bq,
    const float* __restrict__ Wk, const float* __restrict__ bk,
    const float* __restrict__ Wv, const float* __restrict__ bv,
    __bf16* __restrict__ qo, __bf16* __restrict__ ko, __bf16* __restrict__ vpack)
{
    __shared__ float LWq[CK_ * C_];
    __shared__ float LWk[CK_ * C_];
    __shared__ float LWv[C_ * C_];      // row-major [c_out][c_in]
    __shared__ float LX[64][68];        // x tile [c][l], pad 68 (bank spread)
    __shared__ __bf16 Lqs[64 * 8];
    __shared__ __bf16 Lks[64 * 8];

    const int tid = threadIdx.x;
    const int b  = blockIdx.x >> 6;
    const int t  = blockIdx.x & 63;
    const int l0 = t << 6;

    if (tid < 128) {
        ((float4*)LWq)[tid] = ((const float4*)Wq)[tid];
        ((float4*)LWk)[tid] = ((const float4*)Wk)[tid];
    }
    #pragma unroll
    for (int j = 0; j < 4; ++j)
        ((float4*)LWv)[tid + j * 256] = ((const float4*)Wv)[tid + j * 256];
    {   // stage x tile: thread -> row c = tid>>2, quarter part = tid&3
        const int c = tid >> 2, part = tid & 3;
        const float* xrow = x + ((size_t)b * C_ + c) * L_ + l0 + part * 16;
        float4* dst = (float4*)&LX[c][part * 16];
        #pragma unroll
        for (int u = 0; u < 4; ++u) dst[u] = ((const float4*)xrow)[u];
    }
    __syncthreads();

    const int lg = tid & 15;
    const int g  = tid >> 4;

    float va[4][4];
    float qk[4];
    #pragma unroll
    for (int j = 0; j < 4; ++j) {
        float bb = bv[4 * g + j];
        va[j][0] = bb; va[j][1] = bb; va[j][2] = bb; va[j][3] = bb;
    }
    {
        float bb = (g < 8) ? bq[g] : bk[g - 8];
        qk[0] = bb; qk[1] = bb; qk[2] = bb; qk[3] = bb;
    }
    const float* wqk = (g < 8) ? (LWq + g * C_) : (LWk + (g - 8) * C_);

    #pragma unroll 4
    for (int c4 = 0; c4 < 16; ++c4) {
        float4 xv[4];
        #pragma unroll
        for (int u = 0; u < 4; ++u)
            xv[u] = *(const float4*)&LX[4 * c4 + u][lg * 4];
        #pragma unroll
        for (int j = 0; j < 4; ++j) {
            float4 wv = ((const float4*)(LWv + (4 * g + j) * C_))[c4];
            float* a = va[j];
            a[0]=fmaf(wv.x,xv[0].x,a[0]); a[1]=fmaf(wv.x,xv[0].y,a[1]); a[2]=fmaf(wv.x,xv[0].z,a[2]); a[3]=fmaf(wv.x,xv[0].w,a[3]);
            a[0]=fmaf(wv.y,xv[1].x,a[0]); a[1]=fmaf(wv.y,xv[1].y,a[1]); a[2]=fmaf(wv.y,xv[1].z,a[2]); a[3]=fmaf(wv.y,xv[1].w,a[3]);
            a[0]=fmaf(wv.z,xv[2].x,a[0]); a[1]=fmaf(wv.z,xv[2].y,a[1]); a[2]=fmaf(wv.z,xv[2].z,a[2]); a[3]=fmaf(wv.z,xv[2].w,a[3]);
            a[0]=fmaf(wv.w,xv[3].x,a[0]); a[1]=fmaf(wv.w,xv[3].y,a[1]); a[2]=fmaf(wv.w,xv[3].z,a[2]); a[3]=fmaf(wv.w,xv[3].w,a[3]);
        }
        {
            float4 wv = ((const float4*)wqk)[c4];
            qk[0]=fmaf(wv.x,xv[0].x,qk[0]); qk[1]=fmaf(wv.x,xv[0].y,qk[1]); qk[2]=fmaf(wv.x,xv[0].z,qk[2]); qk[3]=fmaf(wv.x,xv[0].w,qk[3]);
            qk[0]=fmaf(wv.y,xv[1].x,qk[0]); qk[1]=fmaf(wv.y,xv[1].y,qk[1]); qk[2]=fmaf(wv.y,xv[1].z,qk[2]); qk[3]=fmaf(wv.y,xv[1].w,qk[3]);
            qk[0]=fmaf(wv.z,xv[2].x,qk[0]); qk[1]=fmaf(wv.z,xv[2].y,qk[1]); qk[2]=fmaf(wv.z,xv[2].z,qk[2]); qk[3]=fmaf(wv.z,xv[2].w,qk[3]);
            qk[0]=fmaf(wv.w,xv[3].x,qk[0]); qk[1]=fmaf(wv.w,xv[3].y,qk[1]); qk[2]=fmaf(wv.w,xv[3].z,qk[2]); qk[3]=fmaf(wv.w,xv[3].w,qk[3]);
        }
    }

    // vpack stores: thread (g,lg) holds c=4g+j, l=l0+4lg+u. (identical)
    {
        __bf16* vt = vpack + ((size_t)b * 64 + t) * 4096;
        const int cb = g >> 2;
        const int sg = lg >> 2;
        const int qd = lg & 3;
        #pragma unroll
        for (int j = 0; j < 4; ++j) {
            bf16x4 vv;
            vv[0]=(__bf16)va[j][0]; vv[1]=(__bf16)va[j][1]; vv[2]=(__bf16)va[j][2]; vv[3]=(__bf16)va[j][3];
            *(bf16x4*)(vt + ((size_t)((cb * 4 + sg) * 64 + qd * 16 + (g & 3) * 4 + j)) * 4) = vv;
        }
    }
    // q/k: gather through LDS, then b128 stores (identical)
    #pragma unroll
    for (int u = 0; u < 4; ++u) {
        if (g < 8) Lqs[(lg * 4 + u) * 8 + g]       = (__bf16)qk[u];
        else       Lks[(lg * 4 + u) * 8 + (g - 8)] = (__bf16)qk[u];
    }
    __syncthreads();
    if (tid < 64) {
        *(bf16x8*)(qo + ((size_t)b * L_ + l0 + tid) * 8) = *(bf16x8*)(Lqs + tid * 8);
        *(bf16x8*)(ko + ((size_t)b * L_ + l0 + tid) * 8) = *(bf16x8*)(Lks + tid * 8);
    }
}

// ---------------- Kernel 2: fused attention ------------------------------
// Byte-identical to the r12 hardware-verified version (attn 53.5us, VGPR 64,
// FETCH 9.8MB, no spill): double-buffered LDS, one barrier/iter, XCD swizzle.
__global__ __launch_bounds__(512, 4) void attn_kernel(
    const __bf16* __restrict__ q, const __bf16* __restrict__ kT,
    const __bf16* __restrict__ VP, const float* __restrict__ x,
    const float* __restrict__ gamma_p, float* __restrict__ out)
{
    __shared__ __bf16 Lv[2][4][4096];   // 64 KB
    __shared__ float  csA[8][16];

    const int tid  = threadIdx.x;
    const int w    = tid >> 6;
    const int lane = tid & 63;
    const int quad = lane >> 4;
    const int l16  = lane & 15;
    const int wh   = w & 3;
    const int lh   = w >> 2;
    const int wg   = blockIdx.x;
    const int b    = wg & 7;            // XCD swizzle
    const int mb   = wg >> 3;
    const int m0   = mb << 6;

    const __bf16* vp = VP + (size_t)b * (64 * 4096);
    const __bf16* qb = q  + (size_t)b * L_ * CK_;

    bf16x8 kf = {};
    if (quad == 0) kf = *(const bf16x8*)(kT + ((size_t)b * L_ + m0 + wh * 16 + l16) * CK_);

    // staging shares: u = w*4+k (0..31): tl = u>>3, seg = u&7.
    const __bf16* gk[4];
    int ok[4];
    #pragma unroll
    for (int k = 0; k < 4; ++k) {
        const int u = w * 4 + k, tl = u >> 3, seg = u & 7;
        gk[k] = vp + (size_t)((tl & 1) * 32 + (tl >> 1)) * 4096 + seg * 512 + lane * 8;
        ok[k] = tl * 4096 + seg * 512 + lane * 8;
    }

    f32x4 acc[4] = {};
    float csum = 0.f;
    bf16x8 r[4];

    // prologue: stage iter 0 into buf0
    #pragma unroll
    for (int k = 0; k < 4; ++k) r[k] = *(const bf16x8*)gk[k];
    #pragma unroll
    for (int k = 0; k < 4; ++k) *(bf16x8*)(&Lv[0][0][0] + ok[k]) = r[k];

    for (int i = 0; i < 16; ++i) {
        __syncthreads();    // publish buf i&1; all reads of buf (i+1)&1 done

        if (i < 15) {       // issue next-iter V loads early (land under compute)
            #pragma unroll
            for (int k = 0; k < 4; ++k)
                r[k] = *(const bf16x8*)(gk[k] + (size_t)(i + 1) * 8192);
        }

        // broadcast q loads for the pair (tiles lh*32+2i, lh*32+2i+1)
        bf16x8 qA[4], qB[4];
        #pragma unroll
        for (int sg = 0; sg < 4; ++sg) {
            qA[sg] = *(const bf16x8*)(qb + (size_t)((lh * 32 + 2 * i)     * 64 + sg * 16 + l16) * CK_);
            qB[sg] = *(const bf16x8*)(qb + (size_t)((lh * 32 + 2 * i + 1) * 64 + sg * 16 + l16) * CK_);
        }

        bf16x4 pkA[4], pkB[4];
        #pragma unroll
        for (int sg = 0; sg < 4; ++sg) {
            f32x4 sv = __builtin_amdgcn_mfma_f32_16x16x32_bf16(qA[sg], kf, (f32x4){0.f,0.f,0.f,0.f}, 0, 0, 0);
            const float e0 = __expf(sv[0]);
            const float e1 = __expf(sv[1]);
            const float e2 = __expf(sv[2]);
            const float e3 = __expf(sv[3]);
            csum += (e0 + e1) + (e2 + e3);
            pkA[sg][0]=(__bf16)e0; pkA[sg][1]=(__bf16)e1; pkA[sg][2]=(__bf16)e2; pkA[sg][3]=(__bf16)e3;
        }
        #pragma unroll
        for (int sg = 0; sg < 4; ++sg) {
            f32x4 sv = __builtin_amdgcn_mfma_f32_16x16x32_bf16(qB[sg], kf, (f32x4){0.f,0.f,0.f,0.f}, 0, 0, 0);
            const float e0 = __expf(sv[0]);
            const float e1 = __expf(sv[1]);
            const float e2 = __expf(sv[2]);
            const float e3 = __expf(sv[3]);
            csum += (e0 + e1) + (e2 + e3);
            pkB[sg][0]=(__bf16)e0; pkB[sg][1]=(__bf16)e1; pkB[sg][2]=(__bf16)e2; pkB[sg][3]=(__bf16)e3;
        }

        const __bf16* LbA = &Lv[i & 1][lh][0];
        const __bf16* LbB = &Lv[i & 1][2 + lh][0];
        #pragma unroll
        for (int sg = 0; sg < 4; ++sg) {
            bf16x8 p8 = __builtin_shufflevector(pkA[sg], pkB[sg], 0, 1, 2, 3, 4, 5, 6, 7);
            #pragma unroll
            for (int cb = 0; cb < 4; ++cb) {
                bf16x4 vfA = *(const bf16x4*)(LbA + ((size_t)((cb * 4 + sg) * 64 + lane)) * 4);
                bf16x4 vfB = *(const bf16x4*)(LbB + ((size_t)((cb * 4 + sg) * 64 + lane)) * 4);
                bf16x8 a8 = __builtin_shufflevector(vfA, vfB, 0, 1, 2, 3, 4, 5, 6, 7);
                acc[cb] = __builtin_amdgcn_mfma_f32_16x16x32_bf16(a8, p8, acc[cb], 0, 0, 0);
            }
        }

        if (i < 15) {       // write-late into the other buffer
            const int nb = (i + 1) & 1;
            #pragma unroll
            for (int k = 0; k < 4; ++k)
                *(bf16x8*)(&Lv[nb][0][0] + ok[k]) = r[k];
        }
    }

    // ---- epilogue: reduce lh=1 into lh=0, normalize, residual ----
    float* Sc = (float*)&Lv[0][0][0];
    if (lh == 1) {
        #pragma unroll
        for (int cb = 0; cb < 4; ++cb)
            #pragma unroll
            for (int r2 = 0; r2 < 4; ++r2)
                Sc[(wh * 64 + cb * 16 + quad * 4 + r2) * 16 + l16] = acc[cb][r2];
    }
    csum += __shfl_xor(csum, 16);
    csum += __shfl_xor(csum, 32);
    if (quad == 0) csA[w][l16] = csum;
    __syncthreads();

    if (lh == 0) {
        const float rinv = gamma_p[0] / (csA[wh][l16] + csA[wh + 4][l16]);
        #pragma unroll
        for (int cb = 0; cb < 4; ++cb) {
            #pragma unroll
            for (int r2 = 0; r2 < 4; ++r2) {
                const int c = cb * 16 + quad * 4 + r2;
                const float vsum = acc[cb][r2] + Sc[(wh * 64 + c) * 16 + l16];
                const size_t idx = ((size_t)(b * 64 + c)) * L_ + m0 + wh * 16 + l16;
                out[idx] = fmaf(rinv, vsum, x[idx]);
            }
        }
    }
}

extern "C" void kernel_launch(void* const* d_in, const int* in_sizes, int n_in,
                              void* d_out, int out_size, void* d_ws, size_t ws_size,
                              hipStream_t stream) {
    const float* x  = (const float*)d_in[0];
    const float* Wq = (const float*)d_in[1];
    const float* bq = (const float*)d_in[2];
    const float* Wk = (const float*)d_in[3];
    const float* bk = (const float*)d_in[4];
    const float* Wv = (const float*)d_in[5];
    const float* bv = (const float*)d_in[6];
    const float* gm = (const float*)d_in[7];
    float* out = (float*)d_out;

    __bf16* ws    = (__bf16*)d_ws;
    __bf16* qo    = ws;                         // 262144 bf16
    __bf16* ko    = ws + 262144;                // 262144 bf16
    __bf16* vpack = ws + 524288;                // 2097152 bf16

    qkv_kernel<<<dim3(B_ * (L_ / 64)), dim3(256), 0, stream>>>(
        x, Wq, bq, Wk, bk, Wv, bv, qo, ko, vpack);
    attn_kernel<<<dim3(B_ * 64), dim3(512), 0, stream>>>(
        qo, ko, vpack, x, gm, out);
}